// Round 12
// baseline (238.238 us; speedup 1.0000x reference)
//
#include <hip/hip_runtime.h>
#include <hip/hip_bf16.h>
#include <math.h>

#define D 256
#define H 8
#define C 32
#define DE 64
#define DF 1024

static inline size_t align_up(size_t x, size_t a) { return (x + a - 1) / a * a; }

typedef __attribute__((ext_vector_type(8))) short short8;
typedef __attribute__((ext_vector_type(4))) float f32x4;

__device__ inline unsigned short f2b(float x) {
    __hip_bfloat16 h = __float2bfloat16(x);
    return *reinterpret_cast<unsigned short*>(&h);
}
__device__ inline float b2f(unsigned short u) {
    return __uint_as_float(((unsigned int)u) << 16);
}

// ---------------- mega-prep: weight transposes + MeT + nf0 convert + deg count ----------------
__global__ void prep_deg_kernel(const float* __restrict__ lin1, const float* __restrict__ lin2,
                                const float* __restrict__ w1, const float* __restrict__ w2,
                                const float* __restrict__ le1, const float* __restrict__ ae1,
                                const float* __restrict__ le2, const float* __restrict__ ae2,
                                const float* __restrict__ nf0, const int* __restrict__ dst,
                                unsigned short* __restrict__ lin1T, unsigned short* __restrict__ lin2T,
                                unsigned short* __restrict__ w1T, unsigned short* __restrict__ w2T,
                                unsigned short* __restrict__ MeT, unsigned short* __restrict__ Abf,
                                int* __restrict__ deg,
                                size_t n_valid, size_t n_total, int cb, int E) {
    int b = blockIdx.x;
    if (b >= 641 + cb) {  // deg count
        int e = (b - 641 - cb) * 256 + threadIdx.x;
        if (e < E) atomicAdd(&deg[dst[e]], 1);
        return;
    }
    if (b > 640) {  // convert nf0 -> Abf (bf16), pad rows zeroed
        size_t i = ((size_t)(b - 641) * 256 + threadIdx.x) * 8;
        if (i >= n_total) return;
        ushort4 o0, o1;
        if (i < n_valid) {
            float4 a = *(const float4*)&nf0[i];
            float4 bb = *(const float4*)&nf0[i + 4];
            o0.x = f2b(a.x); o0.y = f2b(a.y); o0.z = f2b(a.z); o0.w = f2b(a.w);
            o1.x = f2b(bb.x); o1.y = f2b(bb.y); o1.z = f2b(bb.z); o1.w = f2b(bb.w);
        } else {
            o0.x = o0.y = o0.z = o0.w = 0;
            o1 = o0;
        }
        *(ushort4*)&Abf[i] = o0;
        *(ushort4*)&Abf[i + 4] = o1;
        return;
    }
    if (b == 640) {  // MeT[c][d]: c<8 -> layer1 head c; c>=8 -> layer2 head c-8
        for (int t = threadIdx.x; t < 512; t += 256) {
            int d = t >> 3, h = t & 7;
            float s1 = 0.f, s2 = 0.f;
            for (int c = 0; c < C; ++c) {
                s1 += le1[d * (H * C) + h * C + c] * ae1[h * C + c];
                s2 += le2[d * (H * C) + h * C + c] * ae2[h * C + c];
            }
            MeT[h * 64 + d] = f2b(s1);
            MeT[(8 + h) * 64 + d] = f2b(s2);
        }
        return;
    }
    __shared__ float tile[32][33];
    const float* in; unsigned short* outp; int K, N, tt;
    if (b < 64)       { in = lin1; outp = lin1T; K = D;  N = D;  tt = b; }
    else if (b < 128) { in = lin2; outp = lin2T; K = D;  N = D;  tt = b - 64; }
    else if (b < 384) { in = w1;   outp = w1T;   K = D;  N = DF; tt = b - 128; }
    else              { in = w2;   outp = w2T;   K = DF; N = D;  tt = b - 384; }
    int ntn = N >> 5;
    int bn = (tt % ntn) * 32, bk = (tt / ntn) * 32;
    int tx = threadIdx.x & 31, ty = threadIdx.x >> 5;
    for (int i = ty; i < 32; i += 8)
        tile[i][tx] = in[(size_t)(bk + i) * N + bn + tx];
    __syncthreads();
    for (int i = ty; i < 32; i += 8)
        outp[(size_t)(bn + i) * K + bk + tx] = f2b(tile[tx][i]);
}

// ---------------- CSR scan ----------------
__global__ void partial_sum_kernel(const int* __restrict__ deg, int* __restrict__ part, int n) {
    int i = blockIdx.x * 256 + threadIdx.x;
    int v = (i < n) ? deg[i] : 0;
    for (int o = 1; o < 64; o <<= 1) v += __shfl_xor(v, o);
    __shared__ int w4[4];
    if ((threadIdx.x & 63) == 0) w4[threadIdx.x >> 6] = v;
    __syncthreads();
    if (threadIdx.x == 0) part[blockIdx.x] = w4[0] + w4[1] + w4[2] + w4[3];
}

__global__ void scan_final_kernel(const int* __restrict__ deg, const int* __restrict__ part,
                                  int* __restrict__ off, int* __restrict__ cursor, int n) {
    int b = blockIdx.x, t = threadIdx.x, i = b * 256 + t;
    __shared__ int buf[256];
    __shared__ int baseS;
    if (t == 0) {
        int base = 0;
        for (int j = 0; j < b; ++j) base += part[j];
        baseS = base;
    }
    int v = (i < n) ? deg[i] : 0;
    buf[t] = v;
    __syncthreads();
    for (int s = 1; s < 256; s <<= 1) {
        int x = (t >= s) ? buf[t - s] : 0;
        __syncthreads();
        buf[t] += x;
        __syncthreads();
    }
    int excl = baseS + buf[t] - v;
    if (i < n) { off[i] = excl; cursor[i] = excl; }
    if (i == n - 1) off[n] = excl + v;
}

__global__ void fill_kernel(const int* __restrict__ src, const int* __restrict__ dst,
                            int* __restrict__ cursor, int* __restrict__ eid,
                            int* __restrict__ src_csr, int E) {
    int e = blockIdx.x * 256 + threadIdx.x;
    if (e < E) {
        int p = atomicAdd(&cursor[dst[e]], 1);
        eid[p] = e;
        src_csr[p] = src[e];
    }
}

// ---------------- bf16 MFMA GEMM: C = A[MxK] @ BT[NxK]^T (+bias)(+relu) ----------------
template<int BM>
__global__ __launch_bounds__(256) void mfma_gemm_kernel(
    const unsigned short* __restrict__ A, const unsigned short* __restrict__ BT,
    const float* __restrict__ bias, float* __restrict__ Cf, unsigned short* __restrict__ Cb,
    int M, int Nc, int K, int relu,
    const float* __restrict__ a_s, const float* __restrict__ a_d,
    float* __restrict__ asrcO, float* __restrict__ adstO) {
    constexpr int NR = (BM == 128) ? 4 : 2;
    constexpr int AI = BM / 32;
    __shared__ unsigned short As[BM * 64];
    __shared__ unsigned short Bs[128 * 64];
    int t = threadIdx.x;
    int lane = t & 63, w = t >> 6;
    int gm0 = blockIdx.x * BM, gn0 = blockIdx.y * 128;
    f32x4 acc[4][NR] = {};
    int srow = lane >> 3, scol = (lane & 7) * 8;
    int wm = (BM == 128) ? (w >> 1) * 64 : 0;
    int wn = (BM == 128) ? (w & 1) * 64 : w * 32;
    int fr = lane & 15, fk = (lane >> 4) * 8;

    for (int k0 = 0; k0 < K; k0 += 64) {
        __syncthreads();
#pragma unroll
        for (int i = 0; i < AI; ++i) {
            int rb = w * (8 * AI) + i * 8;
            const unsigned short* ga = A + (size_t)(gm0 + rb + srow) * K + k0 + scol;
            __builtin_amdgcn_global_load_lds(
                (const __attribute__((address_space(1))) unsigned int*)ga,
                (__attribute__((address_space(3))) unsigned int*)&As[rb * 64], 16, 0, 0);
        }
#pragma unroll
        for (int i = 0; i < 4; ++i) {
            int rb = w * 32 + i * 8;
            const unsigned short* gb = BT + (size_t)(gn0 + rb + srow) * K + k0 + scol;
            __builtin_amdgcn_global_load_lds(
                (const __attribute__((address_space(1))) unsigned int*)gb,
                (__attribute__((address_space(3))) unsigned int*)&Bs[rb * 64], 16, 0, 0);
        }
        __syncthreads();
#pragma unroll
        for (int kk = 0; kk < 64; kk += 32) {
            short8 a[4], b[NR];
#pragma unroll
            for (int m = 0; m < 4; ++m)
                a[m] = *(const short8*)&As[(wm + m * 16 + fr) * 64 + kk + fk];
#pragma unroll
            for (int n = 0; n < NR; ++n)
                b[n] = *(const short8*)&Bs[(wn + n * 16 + fr) * 64 + kk + fk];
#pragma unroll
            for (int m = 0; m < 4; ++m)
#pragma unroll
                for (int n = 0; n < NR; ++n)
                    acc[m][n] = __builtin_amdgcn_mfma_f32_16x16x32_bf16(a[m], b[n], acc[m][n], 0, 0, 0);
        }
    }
    int fcol = lane & 15, frow4 = (lane >> 4) * 4;
#pragma unroll
    for (int m = 0; m < 4; ++m) {
#pragma unroll
        for (int i = 0; i < 4; ++i) {
            int gr = gm0 + wm + m * 16 + frow4 + i;
            if (gr >= M) continue;
#pragma unroll
            for (int n = 0; n < NR; ++n) {
                int gc = gn0 + wn + n * 16 + fcol;
                float v = acc[m][n][i];
                if (bias) v += bias[gc];
                if (relu) v = fmaxf(v, 0.f);
                if (Cb) Cb[(size_t)gr * Nc + gc] = f2b(v);
                else    Cf[(size_t)gr * Nc + gc] = v;
            }
        }
    }
    if (BM == 64 && a_s) {
        int head = (gn0 >> 5) + w;
        float as0 = a_s[head * 32 + fcol], as1 = a_s[head * 32 + 16 + fcol];
        float ad0 = a_d[head * 32 + fcol], ad1 = a_d[head * 32 + 16 + fcol];
#pragma unroll
        for (int m = 0; m < 4; ++m) {
#pragma unroll
            for (int i = 0; i < 4; ++i) {
                float vs = acc[m][0][i] * as0 + acc[m][1][i] * as1;
                float vd = acc[m][0][i] * ad0 + acc[m][1][i] * ad1;
#pragma unroll
                for (int o = 1; o < 16; o <<= 1) {
                    vs += __shfl_xor(vs, o);
                    vd += __shfl_xor(vd, o);
                }
                int r = gm0 + m * 16 + frow4 + i;
                if (fcol == 0 && r < M) {
                    asrcO[r * 8 + head] = vs;
                    adstO[r * 8 + head] = vd;
                }
            }
        }
    }
}

// ---------------- fused: edge-order ealpha (blocks [0,EAB)) + xs-GEMM layer1 ----------------
// ealpha path reads ew fully COALESCED (edge order), writes eAe[e][16].
__global__ __launch_bounds__(256) void fused_ea_gemm1_kernel(
    const float* __restrict__ ew, const unsigned short* __restrict__ MeT,
    float* __restrict__ eAe, int E, int EAB,
    const unsigned short* __restrict__ A, const unsigned short* __restrict__ BT,
    unsigned short* __restrict__ Cb, int M, int nbx,
    const float* __restrict__ a_s, const float* __restrict__ a_d,
    float* __restrict__ asrcO, float* __restrict__ adstO) {
    __shared__ unsigned short As[64 * 64];
    __shared__ unsigned short Bs[128 * 64];
    int t = threadIdx.x;
    int lane = t & 63, w = t >> 6;

    if ((int)blockIdx.x < EAB) {
        // ---------- edge-order ealpha ----------
        int e0 = blockIdx.x * 64 + w * 16;
        int r = lane & 15, g = lane >> 4;
        int er = e0 + r; if (er > E - 1) er = E - 1;
        const float* rowp = ew + (size_t)er * DE;
        float4 x0 = *(const float4*)&rowp[g * 8];
        float4 x1 = *(const float4*)&rowp[g * 8 + 4];
        float4 y0 = *(const float4*)&rowp[32 + g * 8];
        float4 y1 = *(const float4*)&rowp[32 + g * 8 + 4];
        short8 a0, a1;
        a0[0] = (short)f2b(x0.x); a0[1] = (short)f2b(x0.y); a0[2] = (short)f2b(x0.z); a0[3] = (short)f2b(x0.w);
        a0[4] = (short)f2b(x1.x); a0[5] = (short)f2b(x1.y); a0[6] = (short)f2b(x1.z); a0[7] = (short)f2b(x1.w);
        a1[0] = (short)f2b(y0.x); a1[1] = (short)f2b(y0.y); a1[2] = (short)f2b(y0.z); a1[3] = (short)f2b(y0.w);
        a1[4] = (short)f2b(y1.x); a1[5] = (short)f2b(y1.y); a1[6] = (short)f2b(y1.z); a1[7] = (short)f2b(y1.w);
        short8 b0 = *(const short8*)&MeT[r * 64 + g * 8];
        short8 b1 = *(const short8*)&MeT[r * 64 + 32 + g * 8];
        f32x4 acc = {};
        acc = __builtin_amdgcn_mfma_f32_16x16x32_bf16(a0, b0, acc, 0, 0, 0);
        acc = __builtin_amdgcn_mfma_f32_16x16x32_bf16(a1, b1, acc, 0, 0, 0);
#pragma unroll
        for (int i = 0; i < 4; ++i) {
            int ee = e0 + g * 4 + i;
            if (ee < E) eAe[(size_t)ee * 16 + r] = acc[i];
        }
        return;
    }
    // ---------- GEMM path (BM=64, NR=2) ----------
    int id = blockIdx.x - EAB;
    int bx = id % nbx, by = id / nbx;
    int gm0 = bx * 64, gn0 = by * 128;
    f32x4 acc[4][2] = {};
    int srow = lane >> 3, scol = (lane & 7) * 8;
    int wn = w * 32;
    int fr = lane & 15, fk = (lane >> 4) * 8;

    for (int k0 = 0; k0 < D; k0 += 64) {
        __syncthreads();
#pragma unroll
        for (int i = 0; i < 2; ++i) {
            int rb = w * 16 + i * 8;
            const unsigned short* ga = A + (size_t)(gm0 + rb + srow) * D + k0 + scol;
            __builtin_amdgcn_global_load_lds(
                (const __attribute__((address_space(1))) unsigned int*)ga,
                (__attribute__((address_space(3))) unsigned int*)&As[rb * 64], 16, 0, 0);
        }
#pragma unroll
        for (int i = 0; i < 4; ++i) {
            int rb = w * 32 + i * 8;
            const unsigned short* gb = BT + (size_t)(gn0 + rb + srow) * D + k0 + scol;
            __builtin_amdgcn_global_load_lds(
                (const __attribute__((address_space(1))) unsigned int*)gb,
                (__attribute__((address_space(3))) unsigned int*)&Bs[rb * 64], 16, 0, 0);
        }
        __syncthreads();
#pragma unroll
        for (int kk = 0; kk < 64; kk += 32) {
            short8 a[4], b[2];
#pragma unroll
            for (int m = 0; m < 4; ++m)
                a[m] = *(const short8*)&As[(m * 16 + fr) * 64 + kk + fk];
#pragma unroll
            for (int n = 0; n < 2; ++n)
                b[n] = *(const short8*)&Bs[(wn + n * 16 + fr) * 64 + kk + fk];
#pragma unroll
            for (int m = 0; m < 4; ++m)
#pragma unroll
                for (int n = 0; n < 2; ++n)
                    acc[m][n] = __builtin_amdgcn_mfma_f32_16x16x32_bf16(a[m], b[n], acc[m][n], 0, 0, 0);
        }
    }
    int fcol = lane & 15, frow4 = (lane >> 4) * 4;
#pragma unroll
    for (int m = 0; m < 4; ++m) {
#pragma unroll
        for (int i = 0; i < 4; ++i) {
            int gr = gm0 + m * 16 + frow4 + i;
            if (gr >= M) continue;
#pragma unroll
            for (int n = 0; n < 2; ++n) {
                int gc = gn0 + wn + n * 16 + fcol;
                Cb[(size_t)gr * D + gc] = f2b(acc[m][n][i]);
            }
        }
    }
    {
        int head = (gn0 >> 5) + w;
        float as0 = a_s[head * 32 + fcol], as1 = a_s[head * 32 + 16 + fcol];
        float ad0 = a_d[head * 32 + fcol], ad1 = a_d[head * 32 + 16 + fcol];
#pragma unroll
        for (int m = 0; m < 4; ++m) {
#pragma unroll
            for (int i = 0; i < 4; ++i) {
                float vs = acc[m][0][i] * as0 + acc[m][1][i] * as1;
                float vd = acc[m][0][i] * ad0 + acc[m][1][i] * ad1;
#pragma unroll
                for (int o = 1; o < 16; o <<= 1) {
                    vs += __shfl_xor(vs, o);
                    vd += __shfl_xor(vd, o);
                }
                int r = gm0 + m * 16 + frow4 + i;
                if (fcol == 0 && r < M) {
                    asrcO[r * 8 + head] = vs;
                    adstO[r * 8 + head] = vd;
                }
            }
        }
    }
}

// CSR permute: read eAe[eid[p]] (random 64B from L3-resident 20MB), write coalesced
__global__ void permute_ea_kernel(const float* __restrict__ eAe, const int* __restrict__ eid,
                                  float* __restrict__ eA1c, float* __restrict__ eA2c, int E) {
    int p = blockIdx.x * 256 + threadIdx.x;
    if (p >= E) return;
    int e = eid[p];
    const float4* src = (const float4*)&eAe[(size_t)e * 16];
    float4 v0 = src[0], v1 = src[1], v2 = src[2], v3 = src[3];
    float4* d1 = (float4*)&eA1c[(size_t)p * 8];
    float4* d2 = (float4*)&eA2c[(size_t)p * 8];
    d1[0] = v0; d1[1] = v1;
    d2[0] = v2; d2[1] = v3;
}

// ---------------- FFN2 + LN + leaky + residual, fully fused ----------------
__global__ __launch_bounds__(256) void ffn2_ln_kernel(
    const unsigned short* __restrict__ A, const unsigned short* __restrict__ BT,
    const float* __restrict__ bias, const float* __restrict__ nf_in,
    const float* __restrict__ gamma, const float* __restrict__ beta,
    float* __restrict__ out, int M) {
    __shared__ unsigned short As[64 * 64];
    __shared__ unsigned short Bs[256 * 64];
    __shared__ float redS1[4][64], redS2[4][64];
    __shared__ float muS[64], invS[64];
    int t = threadIdx.x, lane = t & 63, w = t >> 6;
    int gm0 = blockIdx.x * 64;
    f32x4 acc[4][4] = {};
    int srow = lane >> 3, scol = (lane & 7) * 8;
    int wn = w * 64;
    int fr = lane & 15, fk = (lane >> 4) * 8;
    for (int k0 = 0; k0 < DF; k0 += 64) {
        __syncthreads();
#pragma unroll
        for (int i = 0; i < 2; ++i) {
            int rb = w * 16 + i * 8;
            const unsigned short* ga = A + (size_t)(gm0 + rb + srow) * DF + k0 + scol;
            __builtin_amdgcn_global_load_lds(
                (const __attribute__((address_space(1))) unsigned int*)ga,
                (__attribute__((address_space(3))) unsigned int*)&As[rb * 64], 16, 0, 0);
        }
#pragma unroll
        for (int i = 0; i < 8; ++i) {
            int rb = w * 64 + i * 8;
            const unsigned short* gb = BT + (size_t)(rb + srow) * DF + k0 + scol;
            __builtin_amdgcn_global_load_lds(
                (const __attribute__((address_space(1))) unsigned int*)gb,
                (__attribute__((address_space(3))) unsigned int*)&Bs[rb * 64], 16, 0, 0);
        }
        __syncthreads();
#pragma unroll
        for (int kk = 0; kk < 64; kk += 32) {
            short8 a[4], b[4];
#pragma unroll
            for (int m = 0; m < 4; ++m)
                a[m] = *(const short8*)&As[(m * 16 + fr) * 64 + kk + fk];
#pragma unroll
            for (int n = 0; n < 4; ++n)
                b[n] = *(const short8*)&Bs[(wn + n * 16 + fr) * 64 + kk + fk];
#pragma unroll
            for (int m = 0; m < 4; ++m)
#pragma unroll
                for (int n = 0; n < 4; ++n)
                    acc[m][n] = __builtin_amdgcn_mfma_f32_16x16x32_bf16(a[m], b[n], acc[m][n], 0, 0, 0);
        }
    }
    int fcol = lane & 15, frow4 = (lane >> 4) * 4;
#pragma unroll
    for (int m = 0; m < 4; ++m) {
#pragma unroll
        for (int i = 0; i < 4; ++i) {
            float vs1 = 0.f, vs2 = 0.f;
#pragma unroll
            for (int n = 0; n < 4; ++n) {
                float vv = acc[m][n][i] + bias[wn + n * 16 + fcol];
                acc[m][n][i] = vv;
                vs1 += vv; vs2 += vv * vv;
            }
#pragma unroll
            for (int o = 1; o < 16; o <<= 1) {
                vs1 += __shfl_xor(vs1, o);
                vs2 += __shfl_xor(vs2, o);
            }
            if (fcol == 0) {
                redS1[w][m * 16 + frow4 + i] = vs1;
                redS2[w][m * 16 + frow4 + i] = vs2;
            }
        }
    }
    __syncthreads();
    if (t < 64) {
        float s1 = redS1[0][t] + redS1[1][t] + redS1[2][t] + redS1[3][t];
        float s2 = redS2[0][t] + redS2[1][t] + redS2[2][t] + redS2[3][t];
        float mu = s1 / 256.f;
        float var = fmaxf((s2 - 256.f * mu * mu) / 255.f, 0.f);
        muS[t] = mu;
        invS[t] = 1.f / (sqrtf(var) + 1e-6f);
    }
    __syncthreads();
#pragma unroll
    for (int m = 0; m < 4; ++m) {
#pragma unroll
        for (int i = 0; i < 4; ++i) {
            int r = m * 16 + frow4 + i;
            int gr = gm0 + r;
            if (gr >= M) continue;
            float mu = muS[r], inv = invS[r];
#pragma unroll
            for (int n = 0; n < 4; ++n) {
                int gc = wn + n * 16 + fcol;
                float y = gamma[gc] * (acc[m][n][i] - mu) * inv + beta[gc];
                y = y > 0.f ? y : 0.01f * y;
                out[(size_t)gr * D + gc] = nf_in[(size_t)gr * D + gc] + y;
            }
        }
    }
}

// ---------------- GAT: wave-per-node, 3-gen pipelined gather + fused LN ----------------
__global__ __launch_bounds__(256) void gat_node_kernel(
    const int* __restrict__ off, const int* __restrict__ src_csr,
    const float* __restrict__ eAc,
    const float* __restrict__ asrc, const float* __restrict__ adst,
    const unsigned short* __restrict__ xsb, const float* __restrict__ nf_in,
    const float* __restrict__ bias, const float* __restrict__ gamma,
    const float* __restrict__ beta, float* __restrict__ nf_out,
    unsigned short* __restrict__ nf_out_b, int N) {
    int lane = threadIdx.x & 63;
    int n = blockIdx.x * 4 + (threadIdx.x >> 6);
    if (n >= N) return;
    int e0 = off[n], e1 = off[n + 1], deg = e1 - e0;
    int h = lane & 7;
    int hw = lane >> 3;

    float adstn = adst[n * 8 + h];
    float asn = asrc[n * 8 + h];

    float acc0 = 0.f, acc1 = 0.f, acc2 = 0.f, acc3 = 0.f;
    float den0 = 0.f, easum = 0.f;
    int nb8 = (deg + 7) >> 3;

#define LOAD_SE(b, S, EA, A) { A = ((b) * 8 + hw) < deg; int sp_ = e0 + (b) * 8 + hw; \
    S = A ? src_csr[sp_] : n; EA = A ? eAc[(size_t)sp_ * 8 + h] : 0.f; }

    if (nb8 > 0) {
        int s0, s1, s2; float ea0, ea1, ea2; bool a0, a1, a2;
        LOAD_SE(0, s0, ea0, a0);
        LOAD_SE(1, s1, ea1, a1);
        LOAD_SE(2, s2, ea2, a2);
        float as0 = a0 ? asrc[s0 * 8 + h] : 0.f;
        float as1 = a1 ? asrc[s1 * 8 + h] : 0.f;
        ushort4 uA[8], uB[8];
#pragma unroll
        for (int kk = 0; kk < 8; ++kk) {
            int sk = __shfl(s0, kk * 8 + hw);
            uA[kk] = *(const ushort4*)&xsb[(size_t)sk * D + lane * 4];
        }
        int it = 0;
        while (true) {
            if (it + 1 < nb8) {
#pragma unroll
                for (int kk = 0; kk < 8; ++kk) {
                    int sk = __shfl(s1, kk * 8 + hw);
                    uB[kk] = *(const ushort4*)&xsb[(size_t)sk * D + lane * 4];
                }
            }
            {
                float as2 = a2 ? asrc[s2 * 8 + h] : 0.f;
                int s3; float ea3; bool a3;
                LOAD_SE(it + 3, s3, ea3, a3);
                float al = as0 + adstn + ea0;
                al = al > 0.f ? al : 0.2f * al;
                float ex = a0 ? expf(al) : 0.f;
                den0 += ex; easum += ea0;
#pragma unroll
                for (int kk = 0; kk < 8; ++kk) {
                    float exk = __shfl(ex, kk * 8 + hw);
                    acc0 = fmaf(exk, b2f(uA[kk].x), acc0);
                    acc1 = fmaf(exk, b2f(uA[kk].y), acc1);
                    acc2 = fmaf(exk, b2f(uA[kk].z), acc2);
                    acc3 = fmaf(exk, b2f(uA[kk].w), acc3);
                }
                s0 = s1; ea0 = ea1; as0 = as1; a0 = a1;
                s1 = s2; ea1 = ea2; as1 = as2; a1 = a2;
                s2 = s3; ea2 = ea3; a2 = a3;
            }
            if (++it >= nb8) break;
            if (it + 1 < nb8) {
#pragma unroll
                for (int kk = 0; kk < 8; ++kk) {
                    int sk = __shfl(s1, kk * 8 + hw);
                    uA[kk] = *(const ushort4*)&xsb[(size_t)sk * D + lane * 4];
                }
            }
            {
                float as2 = a2 ? asrc[s2 * 8 + h] : 0.f;
                int s3; float ea3; bool a3;
                LOAD_SE(it + 3, s3, ea3, a3);
                float al = as0 + adstn + ea0;
                al = al > 0.f ? al : 0.2f * al;
                float ex = a0 ? expf(al) : 0.f;
                den0 += ex; easum += ea0;
#pragma unroll
                for (int kk = 0; kk < 8; ++kk) {
                    float exk = __shfl(ex, kk * 8 + hw);
                    acc0 = fmaf(exk, b2f(uB[kk].x), acc0);
                    acc1 = fmaf(exk, b2f(uB[kk].y), acc1);
                    acc2 = fmaf(exk, b2f(uB[kk].z), acc2);
                    acc3 = fmaf(exk, b2f(uB[kk].w), acc3);
                }
                s0 = s1; ea0 = ea1; as0 = as1; a0 = a1;
                s1 = s2; ea1 = ea2; as1 = as2; a1 = a2;
                s2 = s3; ea2 = ea3; a2 = a3;
            }
            if (++it >= nb8) break;
        }
    }
#undef LOAD_SE
    den0  += __shfl_xor(den0, 8);
    den0  += __shfl_xor(den0, 16);
    den0  += __shfl_xor(den0, 32);
    easum += __shfl_xor(easum, 8);
    easum += __shfl_xor(easum, 16);
    easum += __shfl_xor(easum, 32);
    float sa = easum / (float)(deg > 0 ? deg : 1);
    float als = asn + adstn + sa;
    als = als > 0.f ? als : 0.2f * als;
    float exSelf = expf(als);
    {
        float exs = __shfl(exSelf, hw);
        ushort4 u = *(const ushort4*)&xsb[(size_t)n * D + lane * 4];
        acc0 = fmaf(exs, b2f(u.x), acc0);
        acc1 = fmaf(exs, b2f(u.y), acc1);
        acc2 = fmaf(exs, b2f(u.z), acc2);
        acc3 = fmaf(exs, b2f(u.w), acc3);
    }
    den0 += exSelf;
    float denOwn = __shfl(den0, hw);
    float inv = 1.f / (denOwn + 1e-16f);

    int t0 = lane * 4;
    float4 bi = *(const float4*)&bias[t0];
    float o0 = acc0 * inv + bi.x;
    float o1 = acc1 * inv + bi.y;
    float o2 = acc2 * inv + bi.z;
    float o3 = acc3 * inv + bi.w;

    float s1r = o0 + o1 + o2 + o3;
    float s2r = o0 * o0 + o1 * o1 + o2 * o2 + o3 * o3;
    for (int o = 1; o < 64; o <<= 1) { s1r += __shfl_xor(s1r, o); s2r += __shfl_xor(s2r, o); }
    float mu = s1r / 256.f;
    float var = fmaxf((s2r - 256.f * mu * mu) / 255.f, 0.f);
    float sdv = sqrtf(var) + 1e-6f;
    float4 ga = *(const float4*)&gamma[t0];
    float4 be = *(const float4*)&beta[t0];
    float4 nin = *(const float4*)&nf_in[(size_t)n * D + t0];
    float y0 = ga.x * (o0 - mu) / sdv + be.x; y0 = y0 > 0.f ? y0 : 0.01f * y0;
    float y1 = ga.y * (o1 - mu) / sdv + be.y; y1 = y1 > 0.f ? y1 : 0.01f * y1;
    float y2 = ga.z * (o2 - mu) / sdv + be.z; y2 = y2 > 0.f ? y2 : 0.01f * y2;
    float y3 = ga.w * (o3 - mu) / sdv + be.w; y3 = y3 > 0.f ? y3 : 0.01f * y3;
    float r0 = nin.x + y0, r1 = nin.y + y1, r2 = nin.z + y2, r3 = nin.w + y3;
    float4 outv; outv.x = r0; outv.y = r1; outv.z = r2; outv.w = r3;
    *(float4*)&nf_out[(size_t)n * D + t0] = outv;
    ushort4 ob; ob.x = f2b(r0); ob.y = f2b(r1); ob.z = f2b(r2); ob.w = f2b(r3);
    *(ushort4*)&nf_out_b[(size_t)n * D + t0] = ob;
}

extern "C" void kernel_launch(void* const* d_in, const int* in_sizes, int n_in,
                              void* d_out, int out_size, void* d_ws, size_t ws_size,
                              hipStream_t stream) {
    const float* nf0    = (const float*)d_in[0];
    const int*   ei     = (const int*)d_in[1];
    const float* ew     = (const float*)d_in[2];
    const float* lin1   = (const float*)d_in[3];
    const float* le1    = (const float*)d_in[4];
    const float* asrc1w = (const float*)d_in[5];
    const float* adst1w = (const float*)d_in[6];
    const float* aedge1 = (const float*)d_in[7];
    const float* b1     = (const float*)d_in[8];
    const float* lin2   = (const float*)d_in[9];
    const float* le2    = (const float*)d_in[10];
    const float* asrc2w = (const float*)d_in[11];
    const float* adst2w = (const float*)d_in[12];
    const float* aedge2 = (const float*)d_in[13];
    const float* b2     = (const float*)d_in[14];
    const float* g1     = (const float*)d_in[15];
    const float* be1    = (const float*)d_in[16];
    const float* g2     = (const float*)d_in[17];
    const float* be2    = (const float*)d_in[18];
    const float* g3     = (const float*)d_in[19];
    const float* be3    = (const float*)d_in[20];
    const float* w1     = (const float*)d_in[21];
    const float* fb1    = (const float*)d_in[22];
    const float* w2     = (const float*)d_in[23];
    const float* fb2    = (const float*)d_in[24];

    const int N = in_sizes[0] / D;
    const int E = in_sizes[1] / 2;
    const int Mpad = ((N + 127) / 128) * 128;
    const int* srcI = ei;
    const int* dstI = ei + E;

    char* ws = (char*)d_ws;
    size_t ob = 0;
    auto alloc = [&](size_t bytes) { void* p = ws + ob; ob = align_up(ob + bytes, 256); return p; };
    // --- arena0: dead after GAT layer 2; start reused as FFN hidden (bf16, Mpad*DF*2 = 20.7MB) ---
    int*   deg     = (int*)alloc((size_t)N * 4);
    int*   csr_off = (int*)alloc((size_t)(N + 1) * 4);
    int*   cursor  = (int*)alloc((size_t)N * 4);
    int*   part    = (int*)alloc(1024);
    int*   eid     = (int*)alloc((size_t)E * 4);
    int*   src_csr = (int*)alloc((size_t)E * 4);
    unsigned short* MeT = (unsigned short*)alloc(16 * 64 * 2);
    float* asrcB   = (float*)alloc((size_t)N * H * 4);
    float* adstB   = (float*)alloc((size_t)N * H * 4);
    float* eAe     = (float*)alloc((size_t)E * 16 * 4);
    float* eA1c    = (float*)alloc((size_t)E * H * 4);
    float* eA2c    = (float*)alloc((size_t)E * H * 4);
    // --- persistent ---
    float* nfw     = (float*)alloc((size_t)N * D * 4);
    unsigned short* xs_b  = (unsigned short*)alloc((size_t)Mpad * D * 2);
    unsigned short* Abf   = (unsigned short*)alloc((size_t)Mpad * D * 2);
    unsigned short* lin1T = (unsigned short*)alloc((size_t)D * D * 2);
    unsigned short* lin2T = (unsigned short*)alloc((size_t)D * D * 2);
    unsigned short* w1T   = (unsigned short*)alloc((size_t)DF * D * 2);
    unsigned short* w2T   = (unsigned short*)alloc((size_t)D * DF * 2);
    unsigned short* hidden = (unsigned short*)ws;  // aliases arena0 (dead by FFN)
    (void)ws_size;
    float* out = (float*)d_out;

    hipMemsetAsync(deg, 0, (size_t)N * 4, stream);

    int eb = (E + 255) / 256;
    int nb = (N + 255) / 256;
    const size_t nvalid = (size_t)N * D, ntot = (size_t)Mpad * D;
    int cb = (int)((ntot / 8 + 255) / 256);

    prep_deg_kernel<<<641 + cb + eb, 256, 0, stream>>>(
        lin1, lin2, w1, w2, le1, aedge1, le2, aedge2, nf0, dstI,
        lin1T, lin2T, w1T, w2T, MeT, Abf, deg, nvalid, ntot, cb, E);
    partial_sum_kernel<<<nb, 256, 0, stream>>>(deg, part, N);
    scan_final_kernel<<<nb, 256, 0, stream>>>(deg, part, csr_off, cursor, N);
    fill_kernel<<<eb, 256, 0, stream>>>(srcI, dstI, cursor, eid, src_csr, E);

    int EAB = (E + 63) / 64;
    int nbx = Mpad / 64;
    int gatb = (N + 3) / 4;

    // ---- edge-order ealpha + GAT-1 xs-GEMM fused (independent paths) ----
    fused_ea_gemm1_kernel<<<EAB + nbx * 2, 256, 0, stream>>>(
        ew, MeT, eAe, E, EAB,
        Abf, lin1T, xs_b, N, nbx, asrc1w, adst1w, asrcB, adstB);
    // ---- CSR permute of eA (L3-resident random reads, coalesced writes) ----
    permute_ea_kernel<<<eb, 256, 0, stream>>>(eAe, eid, eA1c, eA2c, E);

    gat_node_kernel<<<gatb, 256, 0, stream>>>(csr_off, src_csr, eA1c, asrcB, adstB,
                                              xs_b, nf0, b1, g1, be1, nfw, Abf, N);
    // ---- GAT layer 2 ----
    mfma_gemm_kernel<64><<<dim3(nbx, 2), 256, 0, stream>>>(
        Abf, lin2T, nullptr, nullptr, xs_b, N, D, D, 0, asrc2w, adst2w, asrcB, adstB);
    gat_node_kernel<<<gatb, 256, 0, stream>>>(csr_off, src_csr, eA2c, asrcB, adstB,
                                              xs_b, nfw, b2, g2, be2, nfw, Abf, N);
    // ---- FFN ----
    mfma_gemm_kernel<128><<<dim3(Mpad / 128, 8), 256, 0, stream>>>(
        Abf, w1T, fb1, nullptr, hidden, Mpad, DF, D, 1, nullptr, nullptr, nullptr, nullptr);
    ffn2_ln_kernel<<<(N + 63) / 64, 256, 0, stream>>>(hidden, w2T, fb2, nfw, g3, be3, out, N);
}

// Round 13
// 229.218 us; speedup vs baseline: 1.0394x; 1.0394x over previous
//
#include <hip/hip_runtime.h>
#include <hip/hip_bf16.h>
#include <math.h>

#define D 256
#define H 8
#define C 32
#define DE 64
#define DF 1024

static inline size_t align_up(size_t x, size_t a) { return (x + a - 1) / a * a; }

typedef __attribute__((ext_vector_type(8))) short short8;
typedef __attribute__((ext_vector_type(4))) float f32x4;

__device__ inline unsigned short f2b(float x) {
    __hip_bfloat16 h = __float2bfloat16(x);
    return *reinterpret_cast<unsigned short*>(&h);
}
__device__ inline float b2f(unsigned short u) {
    return __uint_as_float(((unsigned int)u) << 16);
}

// ---------------- mega-prep: weight transposes + MeT + nf0 convert + deg count ----------------
__global__ void prep_deg_kernel(const float* __restrict__ lin1, const float* __restrict__ lin2,
                                const float* __restrict__ w1, const float* __restrict__ w2,
                                const float* __restrict__ le1, const float* __restrict__ ae1,
                                const float* __restrict__ le2, const float* __restrict__ ae2,
                                const float* __restrict__ nf0, const int* __restrict__ dst,
                                unsigned short* __restrict__ lin1T, unsigned short* __restrict__ lin2T,
                                unsigned short* __restrict__ w1T, unsigned short* __restrict__ w2T,
                                unsigned short* __restrict__ MeT, unsigned short* __restrict__ Abf,
                                int* __restrict__ deg,
                                size_t n_valid, size_t n_total, int cb, int E) {
    int b = blockIdx.x;
    if (b >= 641 + cb) {  // deg count
        int e = (b - 641 - cb) * 256 + threadIdx.x;
        if (e < E) atomicAdd(&deg[dst[e]], 1);
        return;
    }
    if (b > 640) {  // convert nf0 -> Abf (bf16), pad rows zeroed
        size_t i = ((size_t)(b - 641) * 256 + threadIdx.x) * 8;
        if (i >= n_total) return;
        ushort4 o0, o1;
        if (i < n_valid) {
            float4 a = *(const float4*)&nf0[i];
            float4 bb = *(const float4*)&nf0[i + 4];
            o0.x = f2b(a.x); o0.y = f2b(a.y); o0.z = f2b(a.z); o0.w = f2b(a.w);
            o1.x = f2b(bb.x); o1.y = f2b(bb.y); o1.z = f2b(bb.z); o1.w = f2b(bb.w);
        } else {
            o0.x = o0.y = o0.z = o0.w = 0;
            o1 = o0;
        }
        *(ushort4*)&Abf[i] = o0;
        *(ushort4*)&Abf[i + 4] = o1;
        return;
    }
    if (b == 640) {  // MeT[c][d]: c<8 -> layer1 head c; c>=8 -> layer2 head c-8
        for (int t = threadIdx.x; t < 512; t += 256) {
            int d = t >> 3, h = t & 7;
            float s1 = 0.f, s2 = 0.f;
            for (int c = 0; c < C; ++c) {
                s1 += le1[d * (H * C) + h * C + c] * ae1[h * C + c];
                s2 += le2[d * (H * C) + h * C + c] * ae2[h * C + c];
            }
            MeT[h * 64 + d] = f2b(s1);
            MeT[(8 + h) * 64 + d] = f2b(s2);
        }
        return;
    }
    __shared__ float tile[32][33];
    const float* in; unsigned short* outp; int K, N, tt;
    if (b < 64)       { in = lin1; outp = lin1T; K = D;  N = D;  tt = b; }
    else if (b < 128) { in = lin2; outp = lin2T; K = D;  N = D;  tt = b - 64; }
    else if (b < 384) { in = w1;   outp = w1T;   K = D;  N = DF; tt = b - 128; }
    else              { in = w2;   outp = w2T;   K = DF; N = D;  tt = b - 384; }
    int ntn = N >> 5;
    int bn = (tt % ntn) * 32, bk = (tt / ntn) * 32;
    int tx = threadIdx.x & 31, ty = threadIdx.x >> 5;
    for (int i = ty; i < 32; i += 8)
        tile[i][tx] = in[(size_t)(bk + i) * N + bn + tx];
    __syncthreads();
    for (int i = ty; i < 32; i += 8)
        outp[(size_t)(bn + i) * K + bk + tx] = f2b(tile[tx][i]);
}

// ---------------- CSR scan ----------------
__global__ void partial_sum_kernel(const int* __restrict__ deg, int* __restrict__ part, int n) {
    int i = blockIdx.x * 256 + threadIdx.x;
    int v = (i < n) ? deg[i] : 0;
    for (int o = 1; o < 64; o <<= 1) v += __shfl_xor(v, o);
    __shared__ int w4[4];
    if ((threadIdx.x & 63) == 0) w4[threadIdx.x >> 6] = v;
    __syncthreads();
    if (threadIdx.x == 0) part[blockIdx.x] = w4[0] + w4[1] + w4[2] + w4[3];
}

__global__ void scan_final_kernel(const int* __restrict__ deg, const int* __restrict__ part,
                                  int* __restrict__ off, int* __restrict__ cursor, int n) {
    int b = blockIdx.x, t = threadIdx.x, i = b * 256 + t;
    __shared__ int buf[256];
    __shared__ int baseS;
    if (t == 0) {
        int base = 0;
        for (int j = 0; j < b; ++j) base += part[j];
        baseS = base;
    }
    int v = (i < n) ? deg[i] : 0;
    buf[t] = v;
    __syncthreads();
    for (int s = 1; s < 256; s <<= 1) {
        int x = (t >= s) ? buf[t - s] : 0;
        __syncthreads();
        buf[t] += x;
        __syncthreads();
    }
    int excl = baseS + buf[t] - v;
    if (i < n) { off[i] = excl; cursor[i] = excl; }
    if (i == n - 1) off[n] = excl + v;
}

__global__ void fill_kernel(const int* __restrict__ src, const int* __restrict__ dst,
                            int* __restrict__ cursor, int* __restrict__ eid,
                            int* __restrict__ src_csr, int E) {
    int e = blockIdx.x * 256 + threadIdx.x;
    if (e < E) {
        int p = atomicAdd(&cursor[dst[e]], 1);
        eid[p] = e;
        src_csr[p] = src[e];
    }
}

// ---------------- bf16 MFMA GEMM: C = A[MxK] @ BT[NxK]^T (+bias)(+relu) ----------------
template<int BM>
__global__ __launch_bounds__(256) void mfma_gemm_kernel(
    const unsigned short* __restrict__ A, const unsigned short* __restrict__ BT,
    const float* __restrict__ bias, float* __restrict__ Cf, unsigned short* __restrict__ Cb,
    int M, int Nc, int K, int relu,
    const float* __restrict__ a_s, const float* __restrict__ a_d,
    float* __restrict__ asrcO, float* __restrict__ adstO) {
    constexpr int NR = (BM == 128) ? 4 : 2;
    constexpr int AI = BM / 32;
    __shared__ unsigned short As[BM * 64];
    __shared__ unsigned short Bs[128 * 64];
    int t = threadIdx.x;
    int lane = t & 63, w = t >> 6;
    int gm0 = blockIdx.x * BM, gn0 = blockIdx.y * 128;
    f32x4 acc[4][NR] = {};
    int srow = lane >> 3, scol = (lane & 7) * 8;
    int wm = (BM == 128) ? (w >> 1) * 64 : 0;
    int wn = (BM == 128) ? (w & 1) * 64 : w * 32;
    int fr = lane & 15, fk = (lane >> 4) * 8;

    for (int k0 = 0; k0 < K; k0 += 64) {
        __syncthreads();
#pragma unroll
        for (int i = 0; i < AI; ++i) {
            int rb = w * (8 * AI) + i * 8;
            const unsigned short* ga = A + (size_t)(gm0 + rb + srow) * K + k0 + scol;
            __builtin_amdgcn_global_load_lds(
                (const __attribute__((address_space(1))) unsigned int*)ga,
                (__attribute__((address_space(3))) unsigned int*)&As[rb * 64], 16, 0, 0);
        }
#pragma unroll
        for (int i = 0; i < 4; ++i) {
            int rb = w * 32 + i * 8;
            const unsigned short* gb = BT + (size_t)(gn0 + rb + srow) * K + k0 + scol;
            __builtin_amdgcn_global_load_lds(
                (const __attribute__((address_space(1))) unsigned int*)gb,
                (__attribute__((address_space(3))) unsigned int*)&Bs[rb * 64], 16, 0, 0);
        }
        __syncthreads();
#pragma unroll
        for (int kk = 0; kk < 64; kk += 32) {
            short8 a[4], b[NR];
#pragma unroll
            for (int m = 0; m < 4; ++m)
                a[m] = *(const short8*)&As[(wm + m * 16 + fr) * 64 + kk + fk];
#pragma unroll
            for (int n = 0; n < NR; ++n)
                b[n] = *(const short8*)&Bs[(wn + n * 16 + fr) * 64 + kk + fk];
#pragma unroll
            for (int m = 0; m < 4; ++m)
#pragma unroll
                for (int n = 0; n < NR; ++n)
                    acc[m][n] = __builtin_amdgcn_mfma_f32_16x16x32_bf16(a[m], b[n], acc[m][n], 0, 0, 0);
        }
    }
    int fcol = lane & 15, frow4 = (lane >> 4) * 4;
#pragma unroll
    for (int m = 0; m < 4; ++m) {
#pragma unroll
        for (int i = 0; i < 4; ++i) {
            int gr = gm0 + wm + m * 16 + frow4 + i;
            if (gr >= M) continue;
#pragma unroll
            for (int n = 0; n < NR; ++n) {
                int gc = gn0 + wn + n * 16 + fcol;
                float v = acc[m][n][i];
                if (bias) v += bias[gc];
                if (relu) v = fmaxf(v, 0.f);
                if (Cb) Cb[(size_t)gr * Nc + gc] = f2b(v);
                else    Cf[(size_t)gr * Nc + gc] = v;
            }
        }
    }
    if (BM == 64 && a_s) {
        int head = (gn0 >> 5) + w;
        float as0 = a_s[head * 32 + fcol], as1 = a_s[head * 32 + 16 + fcol];
        float ad0 = a_d[head * 32 + fcol], ad1 = a_d[head * 32 + 16 + fcol];
#pragma unroll
        for (int m = 0; m < 4; ++m) {
#pragma unroll
            for (int i = 0; i < 4; ++i) {
                float vs = acc[m][0][i] * as0 + acc[m][1][i] * as1;
                float vd = acc[m][0][i] * ad0 + acc[m][1][i] * ad1;
#pragma unroll
                for (int o = 1; o < 16; o <<= 1) {
                    vs += __shfl_xor(vs, o);
                    vd += __shfl_xor(vd, o);
                }
                int r = gm0 + m * 16 + frow4 + i;
                if (fcol == 0 && r < M) {
                    asrcO[r * 8 + head] = vs;
                    adstO[r * 8 + head] = vd;
                }
            }
        }
    }
}

// ---------------- fused: CSR-order ealpha (blocks [0,EAB)) + xs-GEMM layer1, BK=32 (12KB LDS) ----------------
__global__ __launch_bounds__(256) void fused_ea_gemm1_kernel(
    const float* __restrict__ ew, const int* __restrict__ eid,
    const unsigned short* __restrict__ MeT,
    float* __restrict__ eA1c, float* __restrict__ eA2c, int E, int EAB,
    const unsigned short* __restrict__ A, const unsigned short* __restrict__ BT,
    unsigned short* __restrict__ Cb, int M, int nbx,
    const float* __restrict__ a_s, const float* __restrict__ a_d,
    float* __restrict__ asrcO, float* __restrict__ adstO) {
    __shared__ unsigned short As[64 * 32];   // 4KB
    __shared__ unsigned short Bs[128 * 32];  // 8KB
    int t = threadIdx.x;
    int lane = t & 63, w = t >> 6;

    if ((int)blockIdx.x < EAB) {
        // ---------- ealpha path (CSR-ordered; random 256B ew row reads, coalesced eA writes) ----------
        int p0 = blockIdx.x * 64 + w * 16;
        int r = lane & 15, g = lane >> 4;
        int pr = p0 + r; if (pr > E - 1) pr = E - 1;
        int er = eid[pr];
        const float* rowp = ew + (size_t)er * DE;
        float4 x0 = *(const float4*)&rowp[g * 8];
        float4 x1 = *(const float4*)&rowp[g * 8 + 4];
        float4 y0 = *(const float4*)&rowp[32 + g * 8];
        float4 y1 = *(const float4*)&rowp[32 + g * 8 + 4];
        short8 a0, a1;
        a0[0] = (short)f2b(x0.x); a0[1] = (short)f2b(x0.y); a0[2] = (short)f2b(x0.z); a0[3] = (short)f2b(x0.w);
        a0[4] = (short)f2b(x1.x); a0[5] = (short)f2b(x1.y); a0[6] = (short)f2b(x1.z); a0[7] = (short)f2b(x1.w);
        a1[0] = (short)f2b(y0.x); a1[1] = (short)f2b(y0.y); a1[2] = (short)f2b(y0.z); a1[3] = (short)f2b(y0.w);
        a1[4] = (short)f2b(y1.x); a1[5] = (short)f2b(y1.y); a1[6] = (short)f2b(y1.z); a1[7] = (short)f2b(y1.w);
        short8 b0 = *(const short8*)&MeT[r * 64 + g * 8];
        short8 b1 = *(const short8*)&MeT[r * 64 + 32 + g * 8];
        f32x4 acc = {};
        acc = __builtin_amdgcn_mfma_f32_16x16x32_bf16(a0, b0, acc, 0, 0, 0);
        acc = __builtin_amdgcn_mfma_f32_16x16x32_bf16(a1, b1, acc, 0, 0, 0);
#pragma unroll
        for (int i = 0; i < 4; ++i) {
            int p = p0 + g * 4 + i;
            if (p < E) {
                if (r < 8) eA1c[(size_t)p * 8 + r] = acc[i];
                else       eA2c[(size_t)p * 8 + (r - 8)] = acc[i];
            }
        }
        return;
    }
    // ---------- GEMM path (BM=64, BK=32, NR=2) ----------
    int id = blockIdx.x - EAB;
    int bx = id % nbx, by = id / nbx;
    int gm0 = bx * 64, gn0 = by * 128;
    f32x4 acc[4][2] = {};
    int srow = lane >> 2, scol = (lane & 3) * 8;  // 16 rows/wave, 4 lanes/row (64B rows)
    int wn = w * 32;
    int fr = lane & 15, fk = (lane >> 4) * 8;

    for (int k0 = 0; k0 < D; k0 += 32) {
        __syncthreads();
        {
            int rb = w * 16;
            const unsigned short* ga = A + (size_t)(gm0 + rb + srow) * D + k0 + scol;
            __builtin_amdgcn_global_load_lds(
                (const __attribute__((address_space(1))) unsigned int*)ga,
                (__attribute__((address_space(3))) unsigned int*)&As[rb * 32], 16, 0, 0);
        }
#pragma unroll
        for (int i = 0; i < 2; ++i) {
            int rb = w * 32 + i * 16;
            const unsigned short* gb = BT + (size_t)(gn0 + rb + srow) * D + k0 + scol;
            __builtin_amdgcn_global_load_lds(
                (const __attribute__((address_space(1))) unsigned int*)gb,
                (__attribute__((address_space(3))) unsigned int*)&Bs[rb * 32], 16, 0, 0);
        }
        __syncthreads();
        short8 a[4], b[2];
#pragma unroll
        for (int m = 0; m < 4; ++m)
            a[m] = *(const short8*)&As[(m * 16 + fr) * 32 + fk];
#pragma unroll
        for (int n = 0; n < 2; ++n)
            b[n] = *(const short8*)&Bs[(wn + n * 16 + fr) * 32 + fk];
#pragma unroll
        for (int m = 0; m < 4; ++m)
#pragma unroll
            for (int n = 0; n < 2; ++n)
                acc[m][n] = __builtin_amdgcn_mfma_f32_16x16x32_bf16(a[m], b[n], acc[m][n], 0, 0, 0);
    }
    int fcol = lane & 15, frow4 = (lane >> 4) * 4;
#pragma unroll
    for (int m = 0; m < 4; ++m) {
#pragma unroll
        for (int i = 0; i < 4; ++i) {
            int gr = gm0 + m * 16 + frow4 + i;
            if (gr >= M) continue;
#pragma unroll
            for (int n = 0; n < 2; ++n) {
                int gc = gn0 + wn + n * 16 + fcol;
                Cb[(size_t)gr * D + gc] = f2b(acc[m][n][i]);
            }
        }
    }
    {
        int head = (gn0 >> 5) + w;
        float as0 = a_s[head * 32 + fcol], as1 = a_s[head * 32 + 16 + fcol];
        float ad0 = a_d[head * 32 + fcol], ad1 = a_d[head * 32 + 16 + fcol];
#pragma unroll
        for (int m = 0; m < 4; ++m) {
#pragma unroll
            for (int i = 0; i < 4; ++i) {
                float vs = acc[m][0][i] * as0 + acc[m][1][i] * as1;
                float vd = acc[m][0][i] * ad0 + acc[m][1][i] * ad1;
#pragma unroll
                for (int o = 1; o < 16; o <<= 1) {
                    vs += __shfl_xor(vs, o);
                    vd += __shfl_xor(vd, o);
                }
                int r = gm0 + m * 16 + frow4 + i;
                if (fcol == 0 && r < M) {
                    asrcO[r * 8 + head] = vs;
                    adstO[r * 8 + head] = vd;
                }
            }
        }
    }
}

// ---------------- FFN2 + LN + leaky + residual, fully fused ----------------
__global__ __launch_bounds__(256) void ffn2_ln_kernel(
    const unsigned short* __restrict__ A, const unsigned short* __restrict__ BT,
    const float* __restrict__ bias, const float* __restrict__ nf_in,
    const float* __restrict__ gamma, const float* __restrict__ beta,
    float* __restrict__ out, int M) {
    __shared__ unsigned short As[64 * 64];
    __shared__ unsigned short Bs[256 * 64];
    __shared__ float redS1[4][64], redS2[4][64];
    __shared__ float muS[64], invS[64];
    int t = threadIdx.x, lane = t & 63, w = t >> 6;
    int gm0 = blockIdx.x * 64;
    f32x4 acc[4][4] = {};
    int srow = lane >> 3, scol = (lane & 7) * 8;
    int wn = w * 64;
    int fr = lane & 15, fk = (lane >> 4) * 8;
    for (int k0 = 0; k0 < DF; k0 += 64) {
        __syncthreads();
#pragma unroll
        for (int i = 0; i < 2; ++i) {
            int rb = w * 16 + i * 8;
            const unsigned short* ga = A + (size_t)(gm0 + rb + srow) * DF + k0 + scol;
            __builtin_amdgcn_global_load_lds(
                (const __attribute__((address_space(1))) unsigned int*)ga,
                (__attribute__((address_space(3))) unsigned int*)&As[rb * 64], 16, 0, 0);
        }
#pragma unroll
        for (int i = 0; i < 8; ++i) {
            int rb = w * 64 + i * 8;
            const unsigned short* gb = BT + (size_t)(rb + srow) * DF + k0 + scol;
            __builtin_amdgcn_global_load_lds(
                (const __attribute__((address_space(1))) unsigned int*)gb,
                (__attribute__((address_space(3))) unsigned int*)&Bs[rb * 64], 16, 0, 0);
        }
        __syncthreads();
#pragma unroll
        for (int kk = 0; kk < 64; kk += 32) {
            short8 a[4], b[4];
#pragma unroll
            for (int m = 0; m < 4; ++m)
                a[m] = *(const short8*)&As[(m * 16 + fr) * 64 + kk + fk];
#pragma unroll
            for (int n = 0; n < 4; ++n)
                b[n] = *(const short8*)&Bs[(wn + n * 16 + fr) * 64 + kk + fk];
#pragma unroll
            for (int m = 0; m < 4; ++m)
#pragma unroll
                for (int n = 0; n < 4; ++n)
                    acc[m][n] = __builtin_amdgcn_mfma_f32_16x16x32_bf16(a[m], b[n], acc[m][n], 0, 0, 0);
        }
    }
    int fcol = lane & 15, frow4 = (lane >> 4) * 4;
#pragma unroll
    for (int m = 0; m < 4; ++m) {
#pragma unroll
        for (int i = 0; i < 4; ++i) {
            float vs1 = 0.f, vs2 = 0.f;
#pragma unroll
            for (int n = 0; n < 4; ++n) {
                float vv = acc[m][n][i] + bias[wn + n * 16 + fcol];
                acc[m][n][i] = vv;
                vs1 += vv; vs2 += vv * vv;
            }
#pragma unroll
            for (int o = 1; o < 16; o <<= 1) {
                vs1 += __shfl_xor(vs1, o);
                vs2 += __shfl_xor(vs2, o);
            }
            if (fcol == 0) {
                redS1[w][m * 16 + frow4 + i] = vs1;
                redS2[w][m * 16 + frow4 + i] = vs2;
            }
        }
    }
    __syncthreads();
    if (t < 64) {
        float s1 = redS1[0][t] + redS1[1][t] + redS1[2][t] + redS1[3][t];
        float s2 = redS2[0][t] + redS2[1][t] + redS2[2][t] + redS2[3][t];
        float mu = s1 / 256.f;
        float var = fmaxf((s2 - 256.f * mu * mu) / 255.f, 0.f);
        muS[t] = mu;
        invS[t] = 1.f / (sqrtf(var) + 1e-6f);
    }
    __syncthreads();
#pragma unroll
    for (int m = 0; m < 4; ++m) {
#pragma unroll
        for (int i = 0; i < 4; ++i) {
            int r = m * 16 + frow4 + i;
            int gr = gm0 + r;
            if (gr >= M) continue;
            float mu = muS[r], inv = invS[r];
#pragma unroll
            for (int n = 0; n < 4; ++n) {
                int gc = wn + n * 16 + fcol;
                float y = gamma[gc] * (acc[m][n][i] - mu) * inv + beta[gc];
                y = y > 0.f ? y : 0.01f * y;
                out[(size_t)gr * D + gc] = nf_in[(size_t)gr * D + gc] + y;
            }
        }
    }
}

// ---------------- GAT: wave-per-node, 3-gen pipelined gather + fused LN ----------------
__global__ __launch_bounds__(256) void gat_node_kernel(
    const int* __restrict__ off, const int* __restrict__ src_csr,
    const float* __restrict__ eAc,
    const float* __restrict__ asrc, const float* __restrict__ adst,
    const unsigned short* __restrict__ xsb, const float* __restrict__ nf_in,
    const float* __restrict__ bias, const float* __restrict__ gamma,
    const float* __restrict__ beta, float* __restrict__ nf_out,
    unsigned short* __restrict__ nf_out_b, int N) {
    int lane = threadIdx.x & 63;
    int n = blockIdx.x * 4 + (threadIdx.x >> 6);
    if (n >= N) return;
    int e0 = off[n], e1 = off[n + 1], deg = e1 - e0;
    int h = lane & 7;
    int hw = lane >> 3;

    float adstn = adst[n * 8 + h];
    float asn = asrc[n * 8 + h];

    float acc0 = 0.f, acc1 = 0.f, acc2 = 0.f, acc3 = 0.f;
    float den0 = 0.f, easum = 0.f;
    int nb8 = (deg + 7) >> 3;

#define LOAD_SE(b, S, EA, A) { A = ((b) * 8 + hw) < deg; int sp_ = e0 + (b) * 8 + hw; \
    S = A ? src_csr[sp_] : n; EA = A ? eAc[(size_t)sp_ * 8 + h] : 0.f; }

    if (nb8 > 0) {
        int s0, s1, s2; float ea0, ea1, ea2; bool a0, a1, a2;
        LOAD_SE(0, s0, ea0, a0);
        LOAD_SE(1, s1, ea1, a1);
        LOAD_SE(2, s2, ea2, a2);
        float as0 = a0 ? asrc[s0 * 8 + h] : 0.f;
        float as1 = a1 ? asrc[s1 * 8 + h] : 0.f;
        ushort4 uA[8], uB[8];
#pragma unroll
        for (int kk = 0; kk < 8; ++kk) {
            int sk = __shfl(s0, kk * 8 + hw);
            uA[kk] = *(const ushort4*)&xsb[(size_t)sk * D + lane * 4];
        }
        int it = 0;
        while (true) {
            if (it + 1 < nb8) {
#pragma unroll
                for (int kk = 0; kk < 8; ++kk) {
                    int sk = __shfl(s1, kk * 8 + hw);
                    uB[kk] = *(const ushort4*)&xsb[(size_t)sk * D + lane * 4];
                }
            }
            {
                float as2 = a2 ? asrc[s2 * 8 + h] : 0.f;
                int s3; float ea3; bool a3;
                LOAD_SE(it + 3, s3, ea3, a3);
                float al = as0 + adstn + ea0;
                al = al > 0.f ? al : 0.2f * al;
                float ex = a0 ? expf(al) : 0.f;
                den0 += ex; easum += ea0;
#pragma unroll
                for (int kk = 0; kk < 8; ++kk) {
                    float exk = __shfl(ex, kk * 8 + hw);
                    acc0 = fmaf(exk, b2f(uA[kk].x), acc0);
                    acc1 = fmaf(exk, b2f(uA[kk].y), acc1);
                    acc2 = fmaf(exk, b2f(uA[kk].z), acc2);
                    acc3 = fmaf(exk, b2f(uA[kk].w), acc3);
                }
                s0 = s1; ea0 = ea1; as0 = as1; a0 = a1;
                s1 = s2; ea1 = ea2; as1 = as2; a1 = a2;
                s2 = s3; ea2 = ea3; a2 = a3;
            }
            if (++it >= nb8) break;
            if (it + 1 < nb8) {
#pragma unroll
                for (int kk = 0; kk < 8; ++kk) {
                    int sk = __shfl(s1, kk * 8 + hw);
                    uA[kk] = *(const ushort4*)&xsb[(size_t)sk * D + lane * 4];
                }
            }
            {
                float as2 = a2 ? asrc[s2 * 8 + h] : 0.f;
                int s3; float ea3; bool a3;
                LOAD_SE(it + 3, s3, ea3, a3);
                float al = as0 + adstn + ea0;
                al = al > 0.f ? al : 0.2f * al;
                float ex = a0 ? expf(al) : 0.f;
                den0 += ex; easum += ea0;
#pragma unroll
                for (int kk = 0; kk < 8; ++kk) {
                    float exk = __shfl(ex, kk * 8 + hw);
                    acc0 = fmaf(exk, b2f(uB[kk].x), acc0);
                    acc1 = fmaf(exk, b2f(uB[kk].y), acc1);
                    acc2 = fmaf(exk, b2f(uB[kk].z), acc2);
                    acc3 = fmaf(exk, b2f(uB[kk].w), acc3);
                }
                s0 = s1; ea0 = ea1; as0 = as1; a0 = a1;
                s1 = s2; ea1 = ea2; as1 = as2; a1 = a2;
                s2 = s3; ea2 = ea3; a2 = a3;
            }
            if (++it >= nb8) break;
        }
    }
#undef LOAD_SE
    den0  += __shfl_xor(den0, 8);
    den0  += __shfl_xor(den0, 16);
    den0  += __shfl_xor(den0, 32);
    easum += __shfl_xor(easum, 8);
    easum += __shfl_xor(easum, 16);
    easum += __shfl_xor(easum, 32);
    float sa = easum / (float)(deg > 0 ? deg : 1);
    float als = asn + adstn + sa;
    als = als > 0.f ? als : 0.2f * als;
    float exSelf = expf(als);
    {
        float exs = __shfl(exSelf, hw);
        ushort4 u = *(const ushort4*)&xsb[(size_t)n * D + lane * 4];
        acc0 = fmaf(exs, b2f(u.x), acc0);
        acc1 = fmaf(exs, b2f(u.y), acc1);
        acc2 = fmaf(exs, b2f(u.z), acc2);
        acc3 = fmaf(exs, b2f(u.w), acc3);
    }
    den0 += exSelf;
    float denOwn = __shfl(den0, hw);
    float inv = 1.f / (denOwn + 1e-16f);

    int t0 = lane * 4;
    float4 bi = *(const float4*)&bias[t0];
    float o0 = acc0 * inv + bi.x;
    float o1 = acc1 * inv + bi.y;
    float o2 = acc2 * inv + bi.z;
    float o3 = acc3 * inv + bi.w;

    float s1r = o0 + o1 + o2 + o3;
    float s2r = o0 * o0 + o1 * o1 + o2 * o2 + o3 * o3;
    for (int o = 1; o < 64; o <<= 1) { s1r += __shfl_xor(s1r, o); s2r += __shfl_xor(s2r, o); }
    float mu = s1r / 256.f;
    float var = fmaxf((s2r - 256.f * mu * mu) / 255.f, 0.f);
    float sdv = sqrtf(var) + 1e-6f;
    float4 ga = *(const float4*)&gamma[t0];
    float4 be = *(const float4*)&beta[t0];
    float4 nin = *(const float4*)&nf_in[(size_t)n * D + t0];
    float y0 = ga.x * (o0 - mu) / sdv + be.x; y0 = y0 > 0.f ? y0 : 0.01f * y0;
    float y1 = ga.y * (o1 - mu) / sdv + be.y; y1 = y1 > 0.f ? y1 : 0.01f * y1;
    float y2 = ga.z * (o2 - mu) / sdv + be.z; y2 = y2 > 0.f ? y2 : 0.01f * y2;
    float y3 = ga.w * (o3 - mu) / sdv + be.w; y3 = y3 > 0.f ? y3 : 0.01f * y3;
    float r0 = nin.x + y0, r1 = nin.y + y1, r2 = nin.z + y2, r3 = nin.w + y3;
    float4 outv; outv.x = r0; outv.y = r1; outv.z = r2; outv.w = r3;
    *(float4*)&nf_out[(size_t)n * D + t0] = outv;
    ushort4 ob; ob.x = f2b(r0); ob.y = f2b(r1); ob.z = f2b(r2); ob.w = f2b(r3);
    *(ushort4*)&nf_out_b[(size_t)n * D + t0] = ob;
}

extern "C" void kernel_launch(void* const* d_in, const int* in_sizes, int n_in,
                              void* d_out, int out_size, void* d_ws, size_t ws_size,
                              hipStream_t stream) {
    const float* nf0    = (const float*)d_in[0];
    const int*   ei     = (const int*)d_in[1];
    const float* ew     = (const float*)d_in[2];
    const float* lin1   = (const float*)d_in[3];
    const float* le1    = (const float*)d_in[4];
    const float* asrc1w = (const float*)d_in[5];
    const float* adst1w = (const float*)d_in[6];
    const float* aedge1 = (const float*)d_in[7];
    const float* b1     = (const float*)d_in[8];
    const float* lin2   = (const float*)d_in[9];
    const float* le2    = (const float*)d_in[10];
    const float* asrc2w = (const float*)d_in[11];
    const float* adst2w = (const float*)d_in[12];
    const float* aedge2 = (const float*)d_in[13];
    const float* b2     = (const float*)d_in[14];
    const float* g1     = (const float*)d_in[15];
    const float* be1    = (const float*)d_in[16];
    const float* g2     = (const float*)d_in[17];
    const float* be2    = (const float*)d_in[18];
    const float* g3     = (const float*)d_in[19];
    const float* be3    = (const float*)d_in[20];
    const float* w1     = (const float*)d_in[21];
    const float* fb1    = (const float*)d_in[22];
    const float* w2     = (const float*)d_in[23];
    const float* fb2    = (const float*)d_in[24];

    const int N = in_sizes[0] / D;
    const int E = in_sizes[1] / 2;
    const int Mpad = ((N + 127) / 128) * 128;
    const int* srcI = ei;
    const int* dstI = ei + E;

    char* ws = (char*)d_ws;
    size_t ob = 0;
    auto alloc = [&](size_t bytes) { void* p = ws + ob; ob = align_up(ob + bytes, 256); return p; };
    // --- arena0: dead after GAT layer 2; start reused as FFN hidden (bf16, Mpad*DF*2 = 20.7MB) ---
    int*   deg     = (int*)alloc((size_t)N * 4);
    int*   csr_off = (int*)alloc((size_t)(N + 1) * 4);
    int*   cursor  = (int*)alloc((size_t)N * 4);
    int*   part    = (int*)alloc(1024);
    int*   eid     = (int*)alloc((size_t)E * 4);
    int*   src_csr = (int*)alloc((size_t)E * 4);
    unsigned short* MeT = (unsigned short*)alloc(16 * 64 * 2);
    float* asrcB   = (float*)alloc((size_t)N * H * 4);
    float* adstB   = (float*)alloc((size_t)N * H * 4);
    float* eA1c    = (float*)alloc((size_t)E * H * 4);
    float* eA2c    = (float*)alloc((size_t)E * H * 4);
    // --- persistent ---
    float* nfw     = (float*)alloc((size_t)N * D * 4);
    unsigned short* xs_b  = (unsigned short*)alloc((size_t)Mpad * D * 2);
    unsigned short* Abf   = (unsigned short*)alloc((size_t)Mpad * D * 2);
    unsigned short* lin1T = (unsigned short*)alloc((size_t)D * D * 2);
    unsigned short* lin2T = (unsigned short*)alloc((size_t)D * D * 2);
    unsigned short* w1T   = (unsigned short*)alloc((size_t)DF * D * 2);
    unsigned short* w2T   = (unsigned short*)alloc((size_t)D * DF * 2);
    unsigned short* hidden = (unsigned short*)ws;  // aliases arena0 (dead by FFN)
    (void)ws_size;
    float* out = (float*)d_out;

    hipMemsetAsync(deg, 0, (size_t)N * 4, stream);

    int eb = (E + 255) / 256;
    int nb = (N + 255) / 256;
    const size_t nvalid = (size_t)N * D, ntot = (size_t)Mpad * D;
    int cb = (int)((ntot / 8 + 255) / 256);

    prep_deg_kernel<<<641 + cb + eb, 256, 0, stream>>>(
        lin1, lin2, w1, w2, le1, aedge1, le2, aedge2, nf0, dstI,
        lin1T, lin2T, w1T, w2T, MeT, Abf, deg, nvalid, ntot, cb, E);
    partial_sum_kernel<<<nb, 256, 0, stream>>>(deg, part, N);
    scan_final_kernel<<<nb, 256, 0, stream>>>(deg, part, csr_off, cursor, N);
    fill_kernel<<<eb, 256, 0, stream>>>(srcI, dstI, cursor, eid, src_csr, E);

    int EAB = (E + 63) / 64;
    int nbx = Mpad / 64;
    int gatb = (N + 3) / 4;

    // ---- CSR-order ealpha + GAT-1 xs-GEMM fused in one dispatch (BK=32 -> 12KB LDS) ----
    fused_ea_gemm1_kernel<<<EAB + nbx * 2, 256, 0, stream>>>(
        ew, eid, MeT, eA1c, eA2c, E, EAB,
        Abf, lin1T, xs_b, N, nbx, asrc1w, adst1w, asrcB, adstB);
    gat_node_kernel<<<gatb, 256, 0, stream>>>(csr_off, src_csr, eA1c, asrcB, adstB,
                                              xs_b, nf0, b1, g1, be1, nfw, Abf, N);
    // ---- GAT layer 2 ----
    mfma_gemm_kernel<64><<<dim3(nbx, 2), 256, 0, stream>>>(
        Abf, lin2T, nullptr, nullptr, xs_b, N, D, D, 0, asrc2w, adst2w, asrcB, adstB);
    gat_node_kernel<<<gatb, 256, 0, stream>>>(csr_off, src_csr, eA2c, asrcB, adstB,
                                              xs_b, nfw, b2, g2, be2, nfw, Abf, N);
    // ---- FFN: hidden = relu(Abf@w1+fb1) for ALL Mpad rows (pad rows zero -> relu(fb1)) ----
    mfma_gemm_kernel<128><<<dim3(Mpad / 128, 8), 256, 0, stream>>>(
        Abf, w1T, fb1, nullptr, hidden, Mpad, DF, D, 1, nullptr, nullptr, nullptr, nullptr);
    // ---- FFN2 + LN + residual + output, fused ----
    ffn2_ln_kernel<<<(N + 63) / 64, 256, 0, stream>>>(hidden, w2T, fb2, nfw, g3, be3, out, N);
}